// Round 1
// baseline (22050.539 us; speedup 1.0000x reference)
//
#include <hip/hip_runtime.h>
#include <math.h>

// ---------------------------------------------------------------------------
// QuantileCombinedModel: 2-layer LSTM encoder (T=128) + autoregressive decoder
// (DEC=325) + linear/pred heads, fully fused in ONE persistent kernel.
//
// Parallelization: 128 WGs, each owns 2 hidden units per layer (8 gate rows),
// weights resident in LDS, cell state in registers. Cross-WG handoff of the
// hidden-state broadcast via workspace + per-WG phase flags (agent-scope
// atomics + fences). Decoder feedback collapsed to 2 phases/step via
// Wc = W_ih0 @ W_lin  (gates0 = relu(h1)@Wc.T + h0@W_hh0.T + b0c).
// ---------------------------------------------------------------------------

#define NW    128
#define NTHR  256

#define II 99      // input size
#define HH 256     // hidden
#define PPQ 9      // predictions per step
#define BB 64      // batch
#define TT 128     // encoder steps
#define DD 325     // decoder steps
#define QTOT 453   // TT + DD

// d_out float offsets: (sensors_forward, sensors_back, yields) concatenated
#define SF_OFF 0
#define SB_OFF (BB*DD*II)            // 2059200
#define Y_OFF  (SB_OFF + BB*TT*II)   // 2870208

// workspace float offsets
#define WS_H0 1024                   // [2][256][64]   (parity, unit, batch)
#define WS_H1 (WS_H0 + 2*256*64)
#define WS_Z  (WS_H1 + 2*256*64)     // [2][128][64]
#define WS_XT (WS_Z  + 2*128*64)     // [128][99][64]  x transposed per step

#define SCOPE_AGENT __HIP_MEMORY_SCOPE_AGENT

__device__ __forceinline__ float sigm(float v) { return 1.0f / (1.0f + expf(-v)); }

__global__ __launch_bounds__(NTHR, 1)
void qcm_kernel(const float* __restrict__ x,
                const float* __restrict__ Wih0, const float* __restrict__ Whh0, const float* __restrict__ b0,
                const float* __restrict__ Wih1, const float* __restrict__ Whh1, const float* __restrict__ b1,
                const float* __restrict__ Wlin, const float* __restrict__ blin,
                const float* __restrict__ Wp1,  const float* __restrict__ bp1,
                const float* __restrict__ Wp2,  const float* __restrict__ bp2,
                float* __restrict__ out, float* __restrict__ ws)
{
  // ---- LDS (≈59 KB) ----
  __shared__ float sStage[4096];     // [64 k][64 b] staging chunk
  __shared__ float sWih0[99*8];      // [k][g]
  __shared__ float sWhh0[2048];      // [k][g] (256x8)
  __shared__ float sWc  [2048];
  __shared__ float sWih1[2048];
  __shared__ float sWhh1[2048];
  __shared__ float sWlin[256];       // W_lin row (wg<99)
  __shared__ float sWp1 [256];       // W_p1 row (z-unit = wg)
  __shared__ float sWp2 [128];       // W_p2 row (wg in [100,109))
  __shared__ float sGates[512];      // [g][b]
  __shared__ float sHead[512];       // [wave][{sens(64), z(64)}]
  __shared__ float sB[32];           // 0..7 b0 | 8..15 b0c | 16..23 b1 | 24 blin 25 bp1 26 bp2

  int*   flags = (int*)ws;
  float* H0 = ws + WS_H0;
  float* H1 = ws + WS_H1;
  float* Zb = ws + WS_Z;
  float* XT = ws + WS_XT;

  const int wg  = (int)blockIdx.x;
  const int tid = (int)threadIdx.x;
  const int wv  = tid >> 6;          // wave 0..3
  const int ln  = tid & 63;
  const int rg  = ln >> 2;           // row group 0..15 (4 rows each)
  const int ks  = (wv << 2) | (ln & 3); // k-sub 0..15
  const int rb  = rg << 2;           // row base
  const int u0  = wg << 1;           // my first hidden unit

  float c0reg = 0.f, c1reg = 0.f;    // cell state for (unit u0+uu, row r) when tid<128

  // ======================= PROLOGUE =======================
  for (int idx = tid; idx < 99*8; idx += NTHR) {
    int k = idx >> 3, g = idx & 7;
    int gate = ((g >> 1) << 8) + u0 + (g & 1);       // gtype*256 + unit
    sWih0[idx] = Wih0[gate*II + k];
  }
  for (int idx = tid; idx < 2048; idx += NTHR) {
    int k = idx >> 3, g = idx & 7;
    int gate = ((g >> 1) << 8) + u0 + (g & 1);
    sWhh0[idx] = Whh0[(gate << 8) + k];
    sWih1[idx] = Wih1[(gate << 8) + k];
    sWhh1[idx] = Whh1[(gate << 8) + k];
  }
  {
    sWlin[tid] = (wg < II) ? Wlin[wg*256 + tid] : 0.f;
    sWp1[tid]  = Wp1[wg*256 + tid];
    if (tid < 128) sWp2[tid] = (wg >= 100 && wg < 109) ? Wp2[(wg-100)*128 + tid] : 0.f;
  }
  if (tid < 8) {
    int gate = ((tid >> 1) << 8) + u0 + (tid & 1);
    sB[tid]      = b0[gate];
    sB[16 + tid] = b1[gate];
  }
  if (tid == 0) {
    sB[24] = (wg < II) ? blin[wg] : 0.f;
    sB[25] = bp1[wg];
    sB[26] = (wg >= 100 && wg < 109) ? bp2[wg-100] : 0.f;
  }
  __syncthreads();
  // Wc slice: sWc[k*8+g] = sum_j W_ih0[gate(g)][j] * W_lin[j][k]
  for (int idx = tid; idx < 2048; idx += NTHR) {
    int k = idx >> 3, g = idx & 7;
    float a = 0.f;
    for (int j = 0; j < II; ++j) a += sWih0[(j << 3) + g] * Wlin[(j << 8) + k];
    sWc[idx] = a;
  }
  if (tid < 8) {  // b0c = b0 + W_ih0 @ b_lin
    float a = 0.f;
    for (int j = 0; j < II; ++j) a += sWih0[(j << 3) + tid] * blin[j];
    sB[8 + tid] = sB[tid] + a;
  }
  // x transpose: this WG handles timestep t = wg  ->  XT[t][i][b]
  for (int idx = tid; idx < II*BB; idx += NTHR) {
    int b = idx & 63, i = idx >> 6;
    __hip_atomic_store(&XT[(size_t)wg*(II*BB) + (i << 6) + b],
                       x[((size_t)b*TT + wg)*II + i], __ATOMIC_RELAXED, SCOPE_AGENT);
  }
  // zero initial hidden state (parity 1 buffers)
  if (tid < 128) {
    int uu = tid >> 6, r = tid & 63;
    __hip_atomic_store(&H0[((256 + u0 + uu) << 6) + r], 0.f, __ATOMIC_RELAXED, SCOPE_AGENT);
    __hip_atomic_store(&H1[((256 + u0 + uu) << 6) + r], 0.f, __ATOMIC_RELAXED, SCOPE_AGENT);
  }
  __syncthreads();
  __builtin_amdgcn_fence(__ATOMIC_RELEASE, "agent");
  if (tid == 0) __hip_atomic_store(&flags[wg], 1, __ATOMIC_RELAXED, SCOPE_AGENT);

  // stage one [64 k][64 b] chunk into LDS (contiguous source, float4)
  auto stage = [&](const float* src, int n4, bool dorelu) {
    const float4* s4 = (const float4*)src;
    float4* d4 = (float4*)sStage;
    #pragma unroll
    for (int i2 = 0; i2 < 4; ++i2) {
      int idx = tid + (i2 << 8);
      if (idx < n4) {
        float4 v = s4[idx];
        if (dorelu) { v.x=fmaxf(v.x,0.f); v.y=fmaxf(v.y,0.f); v.z=fmaxf(v.z,0.f); v.w=fmaxf(v.w,0.f); }
        d4[idx] = v;
      }
    }
  };

  int phi = 1;
  for (int ctr = 0; ctr <= 454; ++ctr) {
    // ========================= PHASE A (layer-0 step) =========================
    ++phi;
    {
      const int tgt = phi - 1;
      if (tid < NW) {
        while (__hip_atomic_load(&flags[tid], __ATOMIC_RELAXED, SCOPE_AGENT) < tgt)
          __builtin_amdgcn_s_sleep(2);
      }
      __syncthreads();
      __builtin_amdgcn_fence(__ATOMIC_ACQUIRE, "agent");
    }
    if (ctr <= 452) {
      float acc[32];
      #pragma unroll
      for (int q = 0; q < 32; ++q) acc[q] = 0.f;
      const int pp = (ctr - 1) & 1;

      auto chunk = [&](const float* wl, int L) {
        for (int k = ks; k < L; k += 16) {
          float4 w0 = *(const float4*)(wl + (k << 3));
          float4 w1 = *(const float4*)(wl + (k << 3) + 4);
          float4 hv = *(const float4*)(sStage + (k << 6) + rb);
          float wr[8] = {w0.x, w0.y, w0.z, w0.w, w1.x, w1.y, w1.z, w1.w};
          #pragma unroll
          for (int g = 0; g < 8; ++g) {
            acc[(g<<2)+0] += wr[g]*hv.x;
            acc[(g<<2)+1] += wr[g]*hv.y;
            acc[(g<<2)+2] += wr[g]*hv.z;
            acc[(g<<2)+3] += wr[g]*hv.w;
          }
        }
      };

      if (ctr < TT) {
        // encoder: gates0 = x_t @ W_ih0.T + h0 @ W_hh0.T + b0
        const float* xt = XT + (size_t)ctr*(II*BB);
        __syncthreads(); stage(xt,        1024, false); __syncthreads(); chunk(sWih0,       64);
        __syncthreads(); stage(xt + 4096,  560, false); __syncthreads(); chunk(sWih0 + 512, 35);
        for (int cc = 0; cc < 4; ++cc) {
          __syncthreads(); stage(H0 + (((pp << 8) + (cc << 6)) << 6), 1024, false);
          __syncthreads(); chunk(sWhh0 + (cc << 9), 64);
        }
      } else {
        // decoder: gates0 = relu(h1) @ Wc.T + h0 @ W_hh0.T + b0c
        for (int cc = 0; cc < 4; ++cc) {
          __syncthreads(); stage(H1 + (((pp << 8) + (cc << 6)) << 6), 1024, true);
          __syncthreads(); chunk(sWc + (cc << 9), 64);
        }
        for (int cc = 0; cc < 4; ++cc) {
          __syncthreads(); stage(H0 + (((pp << 8) + (cc << 6)) << 6), 1024, false);
          __syncthreads(); chunk(sWhh0 + (cc << 9), 64);
        }
      }
      // reduce 16 k-partials -> sGates (+bias)
      const int boff = (ctr < TT) ? 0 : 8;
      __syncthreads();
      for (int o = tid; o < 512; o += NTHR) sGates[o] = sB[boff + (o >> 6)];
      __syncthreads();
      #pragma unroll
      for (int g = 0; g < 8; ++g) {
        #pragma unroll
        for (int j = 0; j < 4; ++j) {
          float v2 = acc[(g<<2)+j];
          v2 += __shfl_xor(v2, 1, 64);
          v2 += __shfl_xor(v2, 2, 64);
          if ((ln & 3) == 0) atomicAdd(&sGates[(g << 6) + rb + j], v2);
        }
      }
      __syncthreads();
      if (tid < 128) { // LSTM cell update, layer 0
        int uu = tid >> 6, r = tid & 63;
        float i_ = sigm (sGates[( uu      << 6) + r]);
        float f_ = sigm (sGates[((2 + uu) << 6) + r]);
        float g_ = tanhf(sGates[((4 + uu) << 6) + r]);
        float o_ = sigm (sGates[((6 + uu) << 6) + r]);
        float c = f_*c0reg + i_*g_;
        c0reg = c;
        float h = o_*tanhf(c);
        __hip_atomic_store(&H0[((((ctr & 1) << 8) + u0 + uu) << 6) + r], h,
                           __ATOMIC_RELAXED, SCOPE_AGENT);
      }
    }
    // yields head (off critical path): yld[ctr-2] from z written at B-(ctr-1)
    if (ctr >= 2 && wg >= 100 && wg < 109 && tid < 64) {
      const float* zp = Zb + ((size_t)(ctr & 1) << 13);
      float y = sB[26];
      #pragma unroll 8
      for (int k = 0; k < 128; ++k) y += zp[(k << 6) + tid] * sWp2[k];
      __hip_atomic_store(&out[Y_OFF + ((size_t)tid*QTOT + (ctr - 2))*PPQ + (wg - 100)], y,
                         __ATOMIC_RELAXED, SCOPE_AGENT);
    }
    { __syncthreads();
      __builtin_amdgcn_fence(__ATOMIC_RELEASE, "agent");
      if (tid == 0) __hip_atomic_store(&flags[wg], phi, __ATOMIC_RELAXED, SCOPE_AGENT); }
    if (ctr == 454) break;

    // ========================= PHASE B (layer-1 step + sens/z heads) =========================
    ++phi;
    {
      const int tgt = phi - 1;
      if (tid < NW) {
        while (__hip_atomic_load(&flags[tid], __ATOMIC_RELAXED, SCOPE_AGENT) < tgt)
          __builtin_amdgcn_s_sleep(2);
      }
      __syncthreads();
      __builtin_amdgcn_fence(__ATOMIC_ACQUIRE, "agent");
    }
    {
      float ps = 0.f, pz = 0.f;               // head partials over my wave's k-slice
      const int pp = (ctr - 1) & 1;

      if (ctr <= 452) {
        float acc[32];
        #pragma unroll
        for (int q = 0; q < 32; ++q) acc[q] = 0.f;

        auto chunk = [&](const float* wl, int L) {
          for (int k = ks; k < L; k += 16) {
            float4 w0 = *(const float4*)(wl + (k << 3));
            float4 w1 = *(const float4*)(wl + (k << 3) + 4);
            float4 hv = *(const float4*)(sStage + (k << 6) + rb);
            float wr[8] = {w0.x, w0.y, w0.z, w0.w, w1.x, w1.y, w1.z, w1.w};
            #pragma unroll
            for (int g = 0; g < 8; ++g) {
              acc[(g<<2)+0] += wr[g]*hv.x;
              acc[(g<<2)+1] += wr[g]*hv.y;
              acc[(g<<2)+2] += wr[g]*hv.z;
              acc[(g<<2)+3] += wr[g]*hv.w;
            }
          }
        };

        // gates1 = h0[ctr] @ W_ih1.T + h1[ctr-1] @ W_hh1.T + b1
        for (int cc = 0; cc < 4; ++cc) {
          __syncthreads(); stage(H0 + ((((ctr & 1) << 8) + (cc << 6)) << 6), 1024, false);
          __syncthreads(); chunk(sWih1 + (cc << 9), 64);
        }
        for (int cc = 0; cc < 4; ++cc) {
          __syncthreads(); stage(H1 + (((pp << 8) + (cc << 6)) << 6), 1024, false);
          __syncthreads(); chunk(sWhh1 + (cc << 9), 64);
          // head partials on resident h1 chunk (sens & z from relu(h1[ctr-1]))
          int k0 = cc << 6;
          #pragma unroll
          for (int t2 = 0; t2 < 16; ++t2) {
            int kk = (wv << 4) + t2;
            float hvv = fmaxf(sStage[(kk << 6) + ln], 0.f);
            ps += hvv * sWlin[k0 + kk];
            pz += hvv * sWp1 [k0 + kk];
          }
        }
        const int boff = 16;
        __syncthreads();
        for (int o = tid; o < 512; o += NTHR) sGates[o] = sB[boff + (o >> 6)];
        __syncthreads();
        #pragma unroll
        for (int g = 0; g < 8; ++g) {
          #pragma unroll
          for (int j = 0; j < 4; ++j) {
            float v2 = acc[(g<<2)+j];
            v2 += __shfl_xor(v2, 1, 64);
            v2 += __shfl_xor(v2, 2, 64);
            if ((ln & 3) == 0) atomicAdd(&sGates[(g << 6) + rb + j], v2);
          }
        }
        __syncthreads();
        if (tid < 128) { // LSTM cell update, layer 1
          int uu = tid >> 6, r = tid & 63;
          float i_ = sigm (sGates[( uu      << 6) + r]);
          float f_ = sigm (sGates[((2 + uu) << 6) + r]);
          float g_ = tanhf(sGates[((4 + uu) << 6) + r]);
          float o_ = sigm (sGates[((6 + uu) << 6) + r]);
          float c = f_*c1reg + i_*g_;
          c1reg = c;
          float h = o_*tanhf(c);
          __hip_atomic_store(&H1[((((ctr & 1) << 8) + u0 + uu) << 6) + r], h,
                             __ATOMIC_RELAXED, SCOPE_AGENT);
        }
      } else { // ctr == 453: heads only (needs h1[452])
        for (int cc = 0; cc < 4; ++cc) {
          __syncthreads(); stage(H1 + (((pp << 8) + (cc << 6)) << 6), 1024, false);
          __syncthreads();
          int k0 = cc << 6;
          #pragma unroll
          for (int t2 = 0; t2 < 16; ++t2) {
            int kk = (wv << 4) + t2;
            float hvv = fmaxf(sStage[(kk << 6) + ln], 0.f);
            ps += hvv * sWlin[k0 + kk];
            pz += hvv * sWp1 [k0 + kk];
          }
        }
      }
      // finalize sens / z for q = ctr-1
      sHead[(wv << 7) + ln]      = ps;
      sHead[(wv << 7) + 64 + ln] = pz;
      __syncthreads();
      if (ctr >= 1 && tid < 64) {
        float s = sHead[tid]      + sHead[128 + tid] + sHead[256 + tid] + sHead[384 + tid] + sB[24];
        float z = fmaxf(sHead[64 + tid] + sHead[192 + tid] + sHead[320 + tid] + sHead[448 + tid] + sB[25], 0.f);
        int q = ctr - 1;
        if (wg < II) {
          size_t o = (q < TT) ? (SB_OFF + ((size_t)tid*TT + q)*II + wg)
                              : (SF_OFF + ((size_t)tid*DD + (q - TT))*II + wg);
          __hip_atomic_store(&out[o], s, __ATOMIC_RELAXED, SCOPE_AGENT);
        }
        __hip_atomic_store(&Zb[((((q & 1) << 7) + wg) << 6) + tid], z,
                           __ATOMIC_RELAXED, SCOPE_AGENT);
      }
    }
    { __syncthreads();
      __builtin_amdgcn_fence(__ATOMIC_RELEASE, "agent");
      if (tid == 0) __hip_atomic_store(&flags[wg], phi, __ATOMIC_RELAXED, SCOPE_AGENT); }
  }
}

extern "C" void kernel_launch(void* const* d_in, const int* in_sizes, int n_in,
                              void* d_out, int out_size, void* d_ws, size_t ws_size,
                              hipStream_t stream) {
  (void)in_sizes; (void)n_in; (void)out_size; (void)ws_size;
  qcm_kernel<<<dim3(NW), dim3(NTHR), 0, stream>>>(
      (const float*)d_in[0],
      (const float*)d_in[1], (const float*)d_in[2], (const float*)d_in[3],
      (const float*)d_in[4], (const float*)d_in[5], (const float*)d_in[6],
      (const float*)d_in[7], (const float*)d_in[8],
      (const float*)d_in[9], (const float*)d_in[10],
      (const float*)d_in[11], (const float*)d_in[12],
      (float*)d_out, (float*)d_ws);
}

// Round 3
// 11870.256 us; speedup vs baseline: 1.8576x; 1.8576x over previous
//
#include <hip/hip_runtime.h>
#include <math.h>

// ---------------------------------------------------------------------------
// QuantileCombinedModel — persistent-kernel LSTM encoder/decoder.
// R1 (resubmit after broker timeout): fence-light sync (no buffer_wbl2),
// direct global->register GEMM operand streaming (no LDS staging, no
// intra-GEMM barriers), shfl+LDS-tree reductions, yields head spread over
// all WGs.  Phase schedule identical to R0 (passed).
// ---------------------------------------------------------------------------

#define NW    128
#define NTHR  256

#define II 99
#define BB 64
#define TT 128
#define DD 325
#define QTOT 453
#define PPQ 9

#define SF_OFF 0
#define SB_OFF (BB*DD*II)            // 2059200
#define Y_OFF  (SB_OFF + BB*TT*II)   // 2870208

#define WS_H0 1024                   // [2][256][64]
#define WS_H1 (WS_H0 + 2*256*64)
#define WS_Z  (WS_H1 + 2*256*64)     // [2][128][64]
#define WS_XT (WS_Z  + 2*128*64)     // [128][99][64]

#define AGENT __HIP_MEMORY_SCOPE_AGENT

__device__ __forceinline__ float sigm(float v){ return 1.0f/(1.0f+expf(-v)); }
__device__ __forceinline__ void st_wt(float* p, float v){ __hip_atomic_store(p, v, __ATOMIC_RELAXED, AGENT); }

__device__ __forceinline__ void fma32(float acc[32], float4 w0, float4 w1, float4 hv) {
  float wr[8] = {w0.x,w0.y,w0.z,w0.w,w1.x,w1.y,w1.z,w1.w};
  #pragma unroll
  for (int g = 0; g < 8; ++g) {
    acc[(g<<2)+0] += wr[g]*hv.x;
    acc[(g<<2)+1] += wr[g]*hv.y;
    acc[(g<<2)+2] += wr[g]*hv.z;
    acc[(g<<2)+3] += wr[g]*hv.w;
  }
}

__global__ __launch_bounds__(NTHR, 1)
void qcm_kernel(const float* __restrict__ x,
                const float* __restrict__ Wih0, const float* __restrict__ Whh0, const float* __restrict__ b0,
                const float* __restrict__ Wih1, const float* __restrict__ Whh1, const float* __restrict__ b1,
                const float* __restrict__ Wlin, const float* __restrict__ blin,
                const float* __restrict__ Wp1,  const float* __restrict__ bp1,
                const float* __restrict__ Wp2,  const float* __restrict__ bp2,
                float* __restrict__ out, float* __restrict__ ws)
{
  // ---- LDS (~56 KB) ----
  __shared__ float sWih0[II*8];      // [k][g]
  __shared__ float sWhh0[2048];
  __shared__ float sWc  [2048];
  __shared__ float sWih1[2048];
  __shared__ float sWhh1[2048];
  __shared__ float sWlin[256];
  __shared__ float sWp1 [256];
  __shared__ float sWp2 [10*128];    // row 9 zeroed (pad)
  __shared__ float sGred[4*512];     // per-wave gate partials
  __shared__ float sGates[512];
  __shared__ float sHs[4*64];        // per-wave sens partials
  __shared__ float sHz[4*64];        // per-wave z partials
  __shared__ float sYred[2][8];
  __shared__ float sB[48];           // 0..7 b0 | 8..15 b0c | 16..23 b1 | 24 blin 25 bp1 | 32..40 bp2

  int*   flags = (int*)ws;
  float* H0 = ws + WS_H0;
  float* H1 = ws + WS_H1;
  float* Zb = ws + WS_Z;
  float* XT = ws + WS_XT;

  const int wg  = (int)blockIdx.x;
  const int tid = (int)threadIdx.x;
  const int wv  = tid >> 6;
  const int ln  = tid & 63;
  const int rg  = ln >> 2;
  const int rb  = rg << 2;              // batch base (4 per thread)
  const int ks  = (wv << 2) | (ln & 3); // k-sub 0..15
  const int u0  = wg << 1;

  float c0 = 0.f, c1 = 0.f;

  // ======================= PROLOGUE =======================
  for (int idx = tid; idx < II*8; idx += NTHR) {
    int k = idx >> 3, g = idx & 7;
    int gate = ((g >> 1) << 8) + u0 + (g & 1);
    sWih0[idx] = Wih0[gate*II + k];
  }
  for (int idx = tid; idx < 2048; idx += NTHR) {
    int k = idx >> 3, g = idx & 7;
    int gate = ((g >> 1) << 8) + u0 + (g & 1);
    sWhh0[idx] = Whh0[(gate << 8) + k];
    sWih1[idx] = Wih1[(gate << 8) + k];
    sWhh1[idx] = Whh1[(gate << 8) + k];
  }
  sWlin[tid] = (wg < II) ? Wlin[wg*256 + tid] : 0.f;
  sWp1[tid]  = Wp1[wg*256 + tid];
  for (int idx = tid; idx < 1280; idx += NTHR) sWp2[idx] = (idx < 1152) ? Wp2[idx] : 0.f;
  if (tid < 8) {
    int gate = ((tid >> 1) << 8) + u0 + (tid & 1);
    sB[tid]      = b0[gate];
    sB[16 + tid] = b1[gate];
  }
  if (tid == 0) {
    sB[24] = (wg < II) ? blin[wg] : 0.f;
    sB[25] = bp1[wg];
  }
  if (tid < 9) sB[32 + tid] = bp2[tid];
  __syncthreads();
  // Wc slice: sWc[k*8+g] = sum_j Wih0[gate(g)][j] * Wlin[j][k]
  for (int idx = tid; idx < 2048; idx += NTHR) {
    int k = idx >> 3, g = idx & 7;
    float a = 0.f;
    for (int j = 0; j < II; ++j) a += sWih0[(j << 3) + g] * Wlin[(j << 8) + k];
    sWc[idx] = a;
  }
  if (tid < 8) {
    float a = 0.f;
    for (int j = 0; j < II; ++j) a += sWih0[(j << 3) + tid] * blin[j];
    sB[8 + tid] = sB[tid] + a;
  }
  // x transpose: WG handles t = wg -> XT[t][i][b]
  for (int idx = tid; idx < II*BB; idx += NTHR) {
    int b = idx & 63, i = idx >> 6;
    st_wt(&XT[(size_t)wg*(II*BB) + (i << 6) + b], x[((size_t)b*TT + wg)*II + i]);
  }
  if (tid < 128) { // zero parity-1 hidden state
    int uu = tid >> 6, r = tid & 63;
    st_wt(&H0[(size_t)((256 + u0 + uu) << 6) + r], 0.f);
    st_wt(&H1[(size_t)((256 + u0 + uu) << 6) + r], 0.f);
  }
  asm volatile("s_waitcnt vmcnt(0)" ::: "memory");
  __syncthreads();
  if (tid == 0) __hip_atomic_store(&flags[wg], 1, __ATOMIC_RELAXED, AGENT);

  int phi = 1;
  for (int ctr = 0; ctr <= 454; ++ctr) {
    // ========================= PHASE A (layer-0 step + yld head) =========================
    ++phi;
    {
      const int tgt = phi - 1;
      if (tid < NW)
        while (__hip_atomic_load(&flags[tid], __ATOMIC_RELAXED, AGENT) < tgt)
          __builtin_amdgcn_s_sleep(2);
      __syncthreads();
      __builtin_amdgcn_fence(__ATOMIC_ACQUIRE, "agent");
    }
    const int bq = wg >> 1, pb = (wg & 1) ? 5 : 0;
    float zv = 0.f;
    if (ctr >= 2 && tid < 128)
      zv = Zb[((size_t)(ctr & 1) << 13) + ((size_t)tid << 6) + bq];   // z[q=ctr-2]

    if (ctr <= 452) {
      float acc[32];
      #pragma unroll
      for (int q2 = 0; q2 < 32; ++q2) acc[q2] = 0.f;
      const int pp = (ctr - 1) & 1;

      if (ctr < TT) {
        // encoder: gates0 = Wih0@x_t + Whh0@h0[prev]
        const float* xb = XT + (size_t)ctr * (II*BB);
        for (int k = ks; k < II; k += 16) {
          float4 hv = *(const float4*)(xb + (k << 6) + rb);
          fma32(acc, *(const float4*)(sWih0 + (k<<3)), *(const float4*)(sWih0 + (k<<3) + 4), hv);
        }
        const float* hb0 = H0 + ((size_t)pp << 14);
        #pragma unroll
        for (int m = 0; m < 16; ++m) {
          int k = ks + (m << 4);
          float4 hv = *(const float4*)(hb0 + (k << 6) + rb);
          fma32(acc, *(const float4*)(sWhh0 + (k<<3)), *(const float4*)(sWhh0 + (k<<3) + 4), hv);
        }
      } else {
        // decoder: gates0 = Wc@relu(h1[prev]) + Whh0@h0[prev]
        const float* hb1 = H1 + ((size_t)pp << 14);
        const float* hb0 = H0 + ((size_t)pp << 14);
        #pragma unroll
        for (int m = 0; m < 16; ++m) {
          int k = ks + (m << 4);
          float4 h1v = *(const float4*)(hb1 + (k << 6) + rb);
          float4 h0v = *(const float4*)(hb0 + (k << 6) + rb);
          h1v.x = fmaxf(h1v.x, 0.f); h1v.y = fmaxf(h1v.y, 0.f);
          h1v.z = fmaxf(h1v.z, 0.f); h1v.w = fmaxf(h1v.w, 0.f);
          fma32(acc, *(const float4*)(sWc   + (k<<3)), *(const float4*)(sWc   + (k<<3) + 4), h1v);
          fma32(acc, *(const float4*)(sWhh0 + (k<<3)), *(const float4*)(sWhh0 + (k<<3) + 4), h0v);
        }
      }
      // gate partial reduce: shfl over (ln&3), per-wave float4 store
      #pragma unroll
      for (int q2 = 0; q2 < 32; ++q2) {
        float v = acc[q2];
        v += __shfl_xor(v, 1, 64); v += __shfl_xor(v, 2, 64);
        acc[q2] = v;
      }
      if ((ln & 3) == 0) {
        #pragma unroll
        for (int g = 0; g < 8; ++g)
          *(float4*)(sGred + (wv << 9) + (g << 6) + rb) =
            make_float4(acc[(g<<2)], acc[(g<<2)+1], acc[(g<<2)+2], acc[(g<<2)+3]);
      }
      // yields head partials (all WGs; 2 WGs per batch)
      if (ctr >= 2 && tid < 128) {
        float yp[5];
        #pragma unroll
        for (int p = 0; p < 5; ++p) yp[p] = zv * sWp2[((pb + p) << 7) + tid];
        #pragma unroll
        for (int p = 0; p < 5; ++p) {
          float v = yp[p];
          v += __shfl_xor(v,1,64); v += __shfl_xor(v,2,64); v += __shfl_xor(v,4,64);
          v += __shfl_xor(v,8,64); v += __shfl_xor(v,16,64); v += __shfl_xor(v,32,64);
          yp[p] = v;
        }
        if (ln == 0) {
          #pragma unroll
          for (int p = 0; p < 5; ++p) sYred[wv][p] = yp[p];
        }
      }
      __syncthreads();
      if (tid < 128) { // gate final sum + bias
        const int boff = (ctr < TT) ? 0 : 8;
        float4 a0 = *(const float4*)(sGred +    0 + (tid<<2));
        float4 a1 = *(const float4*)(sGred +  512 + (tid<<2));
        float4 a2 = *(const float4*)(sGred + 1024 + (tid<<2));
        float4 a3 = *(const float4*)(sGred + 1536 + (tid<<2));
        float bias = sB[boff + (tid >> 4)];
        float4 r;
        r.x = a0.x+a1.x+a2.x+a3.x + bias;
        r.y = a0.y+a1.y+a2.y+a3.y + bias;
        r.z = a0.z+a1.z+a2.z+a3.z + bias;
        r.w = a0.w+a1.w+a2.w+a3.w + bias;
        *(float4*)(sGates + (tid<<2)) = r;
      }
      __syncthreads();
      if (tid < 128) { // LSTM cell, layer 0
        int uu = tid >> 6, r = tid & 63;
        float i_ = sigm (sGates[( uu      << 6) + r]);
        float f_ = sigm (sGates[((2 + uu) << 6) + r]);
        float g_ = tanhf(sGates[((4 + uu) << 6) + r]);
        float o_ = sigm (sGates[((6 + uu) << 6) + r]);
        float c = f_*c0 + i_*g_;
        c0 = c;
        st_wt(&H0[((size_t)(((ctr & 1) << 8) + u0 + uu) << 6) + r], o_*tanhf(c));
      }
      if (ctr >= 2 && tid >= 192 && tid < 197) {
        int p = tid - 192;
        if (pb + p < 9) {
          float y = sYred[0][p] + sYred[1][p] + sB[32 + pb + p];
          st_wt(&out[Y_OFF + ((size_t)bq*QTOT + (ctr - 2))*PPQ + pb + p], y);
        }
      }
    } else { // ctr = 453/454: yields head only
      if (tid < 128) {
        float yp[5];
        #pragma unroll
        for (int p = 0; p < 5; ++p) yp[p] = zv * sWp2[((pb + p) << 7) + tid];
        #pragma unroll
        for (int p = 0; p < 5; ++p) {
          float v = yp[p];
          v += __shfl_xor(v,1,64); v += __shfl_xor(v,2,64); v += __shfl_xor(v,4,64);
          v += __shfl_xor(v,8,64); v += __shfl_xor(v,16,64); v += __shfl_xor(v,32,64);
          yp[p] = v;
        }
        if (ln == 0) {
          #pragma unroll
          for (int p = 0; p < 5; ++p) sYred[wv][p] = yp[p];
        }
      }
      __syncthreads();
      if (tid >= 192 && tid < 197) {
        int p = tid - 192;
        if (pb + p < 9) {
          float y = sYred[0][p] + sYred[1][p] + sB[32 + pb + p];
          st_wt(&out[Y_OFF + ((size_t)bq*QTOT + (ctr - 2))*PPQ + pb + p], y);
        }
      }
    }
    asm volatile("s_waitcnt vmcnt(0)" ::: "memory");
    __syncthreads();
    if (tid == 0) __hip_atomic_store(&flags[wg], phi, __ATOMIC_RELAXED, AGENT);
    if (ctr == 454) break;

    // ========================= PHASE B (layer-1 step + sens/z heads) =========================
    ++phi;
    {
      const int tgt = phi - 1;
      if (tid < NW)
        while (__hip_atomic_load(&flags[tid], __ATOMIC_RELAXED, AGENT) < tgt)
          __builtin_amdgcn_s_sleep(2);
      __syncthreads();
      __builtin_amdgcn_fence(__ATOMIC_ACQUIRE, "agent");
    }
    {
      const int pp = (ctr - 1) & 1, cur = ctr & 1;
      float ps[4] = {0,0,0,0}, pz[4] = {0,0,0,0};

      if (ctr <= 452) {
        float acc[32];
        #pragma unroll
        for (int q2 = 0; q2 < 32; ++q2) acc[q2] = 0.f;

        const float* hbA = H0 + ((size_t)cur << 14);   // h0[ctr]
        const float* hbB = H1 + ((size_t)pp  << 14);   // h1[ctr-1]
        #pragma unroll
        for (int m = 0; m < 16; ++m) {
          int k = ks + (m << 4);
          float4 hv0 = *(const float4*)(hbA + (k << 6) + rb);
          float4 hv1 = *(const float4*)(hbB + (k << 6) + rb);
          fma32(acc, *(const float4*)(sWih1 + (k<<3)), *(const float4*)(sWih1 + (k<<3) + 4), hv0);
          fma32(acc, *(const float4*)(sWhh1 + (k<<3)), *(const float4*)(sWhh1 + (k<<3) + 4), hv1);
          float rx = fmaxf(hv1.x,0.f), ry = fmaxf(hv1.y,0.f), rz = fmaxf(hv1.z,0.f), rw = fmaxf(hv1.w,0.f);
          float wl = sWlin[k], wp = sWp1[k];
          ps[0] += rx*wl; ps[1] += ry*wl; ps[2] += rz*wl; ps[3] += rw*wl;
          pz[0] += rx*wp; pz[1] += ry*wp; pz[2] += rz*wp; pz[3] += rw*wp;
        }
        #pragma unroll
        for (int q2 = 0; q2 < 32; ++q2) {
          float v = acc[q2];
          v += __shfl_xor(v, 1, 64); v += __shfl_xor(v, 2, 64);
          acc[q2] = v;
        }
        #pragma unroll
        for (int j = 0; j < 4; ++j) {
          float v = ps[j]; v += __shfl_xor(v,1,64); v += __shfl_xor(v,2,64); ps[j] = v;
          v = pz[j]; v += __shfl_xor(v,1,64); v += __shfl_xor(v,2,64); pz[j] = v;
        }
        if ((ln & 3) == 0) {
          #pragma unroll
          for (int g = 0; g < 8; ++g)
            *(float4*)(sGred + (wv << 9) + (g << 6) + rb) =
              make_float4(acc[(g<<2)], acc[(g<<2)+1], acc[(g<<2)+2], acc[(g<<2)+3]);
          *(float4*)(sHs + (wv << 6) + rb) = make_float4(ps[0],ps[1],ps[2],ps[3]);
          *(float4*)(sHz + (wv << 6) + rb) = make_float4(pz[0],pz[1],pz[2],pz[3]);
        }
        __syncthreads();
        if (tid < 128) {
          float4 a0 = *(const float4*)(sGred +    0 + (tid<<2));
          float4 a1 = *(const float4*)(sGred +  512 + (tid<<2));
          float4 a2 = *(const float4*)(sGred + 1024 + (tid<<2));
          float4 a3 = *(const float4*)(sGred + 1536 + (tid<<2));
          float bias = sB[16 + (tid >> 4)];
          float4 r;
          r.x = a0.x+a1.x+a2.x+a3.x + bias;
          r.y = a0.y+a1.y+a2.y+a3.y + bias;
          r.z = a0.z+a1.z+a2.z+a3.z + bias;
          r.w = a0.w+a1.w+a2.w+a3.w + bias;
          *(float4*)(sGates + (tid<<2)) = r;
        } else if (tid < 192 && ctr >= 1) { // sens/z finalize, q = ctr-1
          int b = tid - 128, q = ctr - 1;
          float s = sHs[b] + sHs[64+b] + sHs[128+b] + sHs[192+b] + sB[24];
          float z = fmaxf(sHz[b] + sHz[64+b] + sHz[128+b] + sHz[192+b] + sB[25], 0.f);
          if (wg < II) {
            size_t o = (q < TT) ? (SB_OFF + ((size_t)b*TT + q)*II + wg)
                                : (SF_OFF + ((size_t)b*DD + (q - TT))*II + wg);
            st_wt(&out[o], s);
          }
          st_wt(&Zb[((size_t)(q & 1) << 13) + ((size_t)wg << 6) + b], z);
        }
        __syncthreads();
        if (tid < 128) { // LSTM cell, layer 1
          int uu = tid >> 6, r = tid & 63;
          float i_ = sigm (sGates[( uu      << 6) + r]);
          float f_ = sigm (sGates[((2 + uu) << 6) + r]);
          float g_ = tanhf(sGates[((4 + uu) << 6) + r]);
          float o_ = sigm (sGates[((6 + uu) << 6) + r]);
          float c = f_*c1 + i_*g_;
          c1 = c;
          st_wt(&H1[((size_t)((cur << 8) + u0 + uu) << 6) + r], o_*tanhf(c));
        }
      } else { // ctr == 453: heads only from h1[452]
        const float* hbB = H1 + ((size_t)pp << 14);
        #pragma unroll
        for (int m = 0; m < 16; ++m) {
          int k = ks + (m << 4);
          float4 hv1 = *(const float4*)(hbB + (k << 6) + rb);
          float rx = fmaxf(hv1.x,0.f), ry = fmaxf(hv1.y,0.f), rz = fmaxf(hv1.z,0.f), rw = fmaxf(hv1.w,0.f);
          float wl = sWlin[k], wp = sWp1[k];
          ps[0] += rx*wl; ps[1] += ry*wl; ps[2] += rz*wl; ps[3] += rw*wl;
          pz[0] += rx*wp; pz[1] += ry*wp; pz[2] += rz*wp; pz[3] += rw*wp;
        }
        #pragma unroll
        for (int j = 0; j < 4; ++j) {
          float v = ps[j]; v += __shfl_xor(v,1,64); v += __shfl_xor(v,2,64); ps[j] = v;
          v = pz[j]; v += __shfl_xor(v,1,64); v += __shfl_xor(v,2,64); pz[j] = v;
        }
        if ((ln & 3) == 0) {
          *(float4*)(sHs + (wv << 6) + rb) = make_float4(ps[0],ps[1],ps[2],ps[3]);
          *(float4*)(sHz + (wv << 6) + rb) = make_float4(pz[0],pz[1],pz[2],pz[3]);
        }
        __syncthreads();
        if (tid >= 128 && tid < 192) {
          int b = tid - 128, q = ctr - 1;
          float s = sHs[b] + sHs[64+b] + sHs[128+b] + sHs[192+b] + sB[24];
          float z = fmaxf(sHz[b] + sHz[64+b] + sHz[128+b] + sHz[192+b] + sB[25], 0.f);
          if (wg < II) {
            size_t o = SF_OFF + ((size_t)b*DD + (q - TT))*II + wg;
            st_wt(&out[o], s);
          }
          st_wt(&Zb[((size_t)(q & 1) << 13) + ((size_t)wg << 6) + b], z);
        }
      }
    }
    asm volatile("s_waitcnt vmcnt(0)" ::: "memory");
    __syncthreads();
    if (tid == 0) __hip_atomic_store(&flags[wg], phi, __ATOMIC_RELAXED, AGENT);
  }
}

extern "C" void kernel_launch(void* const* d_in, const int* in_sizes, int n_in,
                              void* d_out, int out_size, void* d_ws, size_t ws_size,
                              hipStream_t stream) {
  (void)in_sizes; (void)n_in; (void)out_size; (void)ws_size;
  qcm_kernel<<<dim3(NW), dim3(NTHR), 0, stream>>>(
      (const float*)d_in[0],
      (const float*)d_in[1], (const float*)d_in[2], (const float*)d_in[3],
      (const float*)d_in[4], (const float*)d_in[5], (const float*)d_in[6],
      (const float*)d_in[7], (const float*)d_in[8],
      (const float*)d_in[9], (const float*)d_in[10],
      (const float*)d_in[11], (const float*)d_in[12],
      (float*)d_out, (float*)d_ws);
}

// Round 6
// 11528.426 us; speedup vs baseline: 1.9127x; 1.0297x over previous
//
#include <hip/hip_runtime.h>
#include <math.h>

// ---------------------------------------------------------------------------
// QuantileCombinedModel — persistent-kernel LSTM encoder/decoder.
// R5: R1 structure (measured 11.87 ms, passed) minus the per-phase agent
// acquire fence (buffer_inv).  All cross-WG data reads (H0/H1/Zb/XT) are now
// compiler-tracked coherent loads: __hip_atomic_load relaxed/agent at 8B
// granularity (same coherence path as the proven flag loads).  No inline-asm
// data loads, no manual vmcnt counting (R3's crash: RA spilled untracked
// async asm outputs).  Release side / flag protocol unchanged.
// ---------------------------------------------------------------------------

#define NW    128
#define NTHR  256

#define II 99
#define BB 64
#define TT 128
#define DD 325
#define QTOT 453
#define PPQ 9

#define SF_OFF 0
#define SB_OFF (BB*DD*II)            // 2059200
#define Y_OFF  (SB_OFF + BB*TT*II)   // 2870208

#define WS_H0 1024                   // [2][256][64]
#define WS_H1 (WS_H0 + 2*256*64)
#define WS_Z  (WS_H1 + 2*256*64)     // [2][128][64]
#define WS_XT (WS_Z  + 2*128*64)     // [128][99][64]

#define AGENT __HIP_MEMORY_SCOPE_AGENT

typedef float f4 __attribute__((ext_vector_type(4)));

__device__ __forceinline__ float sigm(float v){ return 1.0f/(1.0f+expf(-v)); }
__device__ __forceinline__ void st_wt(float* p, float v){ __hip_atomic_store(p, v, __ATOMIC_RELAXED, AGENT); }

// coherent 8B load (agent scope -> reads the coherence point, compiler-tracked)
__device__ __forceinline__ float2 ld2c(const float* p) {
  unsigned long long v = __hip_atomic_load((const unsigned long long*)p, __ATOMIC_RELAXED, AGENT);
  float2 r;
  r.x = __uint_as_float((unsigned)v);
  r.y = __uint_as_float((unsigned)(v >> 32));
  return r;
}
// coherent 16B fragment as two tracked 8B loads
__device__ __forceinline__ f4 ld4c(const float* p) {
  float2 a = ld2c(p), b = ld2c(p + 2);
  f4 r; r.x = a.x; r.y = a.y; r.z = b.x; r.w = b.y;
  return r;
}

__device__ __forceinline__ void fma32(float acc[32], f4 w0, f4 w1, f4 hv) {
  float wr[8] = {w0.x,w0.y,w0.z,w0.w,w1.x,w1.y,w1.z,w1.w};
  #pragma unroll
  for (int g = 0; g < 8; ++g) {
    acc[(g<<2)+0] += wr[g]*hv.x;
    acc[(g<<2)+1] += wr[g]*hv.y;
    acc[(g<<2)+2] += wr[g]*hv.z;
    acc[(g<<2)+3] += wr[g]*hv.w;
  }
}

__global__ __launch_bounds__(NTHR, 1)
void qcm_kernel(const float* __restrict__ x,
                const float* __restrict__ Wih0, const float* __restrict__ Whh0, const float* __restrict__ b0,
                const float* __restrict__ Wih1, const float* __restrict__ Whh1, const float* __restrict__ b1,
                const float* __restrict__ Wlin, const float* __restrict__ blin,
                const float* __restrict__ Wp1,  const float* __restrict__ bp1,
                const float* __restrict__ Wp2,  const float* __restrict__ bp2,
                float* __restrict__ out, float* __restrict__ ws)
{
  // ---- LDS (~56 KB) ----
  __shared__ float sWih0[II*8];      // [k][g]
  __shared__ float sWhh0[2048];
  __shared__ float sWc  [2048];
  __shared__ float sWih1[2048];
  __shared__ float sWhh1[2048];
  __shared__ float sWlin[256];
  __shared__ float sWp1 [256];
  __shared__ float sWp2 [10*128];    // row 9 zeroed (pad)
  __shared__ float sGred[4*512];     // per-wave gate partials
  __shared__ float sGates[512];
  __shared__ float sHs[4*64];        // per-wave sens partials
  __shared__ float sHz[4*64];        // per-wave z partials
  __shared__ float sYred[2][8];
  __shared__ float sB[48];           // 0..7 b0 | 8..15 b0c | 16..23 b1 | 24 blin 25 bp1 | 32..40 bp2

  int*   flags = (int*)ws;
  float* H0 = ws + WS_H0;
  float* H1 = ws + WS_H1;
  float* Zb = ws + WS_Z;
  float* XT = ws + WS_XT;

  const int wg  = (int)blockIdx.x;
  const int tid = (int)threadIdx.x;
  const int wv  = tid >> 6;
  const int ln  = tid & 63;
  const int rg  = ln >> 2;
  const int rb  = rg << 2;              // batch base (4 per thread)
  const int ks  = (wv << 2) | (ln & 3); // k-sub 0..15
  const int u0  = wg << 1;

  float c0 = 0.f, c1 = 0.f;

  // ======================= PROLOGUE =======================
  for (int idx = tid; idx < II*8; idx += NTHR) {
    int k = idx >> 3, g = idx & 7;
    int gate = ((g >> 1) << 8) + u0 + (g & 1);
    sWih0[idx] = Wih0[gate*II + k];
  }
  for (int idx = tid; idx < 2048; idx += NTHR) {
    int k = idx >> 3, g = idx & 7;
    int gate = ((g >> 1) << 8) + u0 + (g & 1);
    sWhh0[idx] = Whh0[(gate << 8) + k];
    sWih1[idx] = Wih1[(gate << 8) + k];
    sWhh1[idx] = Whh1[(gate << 8) + k];
  }
  sWlin[tid] = (wg < II) ? Wlin[wg*256 + tid] : 0.f;
  sWp1[tid]  = Wp1[wg*256 + tid];
  for (int idx = tid; idx < 1280; idx += NTHR) sWp2[idx] = (idx < 1152) ? Wp2[idx] : 0.f;
  if (tid < 8) {
    int gate = ((tid >> 1) << 8) + u0 + (tid & 1);
    sB[tid]      = b0[gate];
    sB[16 + tid] = b1[gate];
  }
  if (tid == 0) {
    sB[24] = (wg < II) ? blin[wg] : 0.f;
    sB[25] = bp1[wg];
  }
  if (tid < 9) sB[32 + tid] = bp2[tid];
  __syncthreads();
  // Wc slice: sWc[k*8+g] = sum_j Wih0[gate(g)][j] * Wlin[j][k]
  for (int idx = tid; idx < 2048; idx += NTHR) {
    int k = idx >> 3, g = idx & 7;
    float a = 0.f;
    for (int j = 0; j < II; ++j) a += sWih0[(j << 3) + g] * Wlin[(j << 8) + k];
    sWc[idx] = a;
  }
  if (tid < 8) {
    float a = 0.f;
    for (int j = 0; j < II; ++j) a += sWih0[(j << 3) + tid] * blin[j];
    sB[8 + tid] = sB[tid] + a;
  }
  // x transpose: WG handles t = wg -> XT[t][i][b]
  for (int idx = tid; idx < II*BB; idx += NTHR) {
    int b = idx & 63, i = idx >> 6;
    st_wt(&XT[(size_t)wg*(II*BB) + (i << 6) + b], x[((size_t)b*TT + wg)*II + i]);
  }
  if (tid < 128) { // zero parity-1 hidden state
    int uu = tid >> 6, r = tid & 63;
    st_wt(&H0[(size_t)((256 + u0 + uu) << 6) + r], 0.f);
    st_wt(&H1[(size_t)((256 + u0 + uu) << 6) + r], 0.f);
  }
  asm volatile("s_waitcnt vmcnt(0)" ::: "memory");
  __syncthreads();
  if (tid == 0) __hip_atomic_store(&flags[wg], 1, __ATOMIC_RELAXED, AGENT);

  int phi = 1;
  for (int ctr = 0; ctr <= 454; ++ctr) {
    // ========================= PHASE A (layer-0 step + yld head) =========================
    ++phi;
    {
      const int tgt = phi - 1;
      if (tid < NW)
        while (__hip_atomic_load(&flags[tid], __ATOMIC_RELAXED, AGENT) < tgt)
          __builtin_amdgcn_s_sleep(2);
      __syncthreads();
    }
    const int bq = wg >> 1, pb = (wg & 1) ? 5 : 0;

    if (ctr <= 452) {
      float acc[32];
      #pragma unroll
      for (int q2 = 0; q2 < 32; ++q2) acc[q2] = 0.f;
      const int pp = (ctr - 1) & 1;

      if (ctr < TT) {
        // encoder: gates0 = Wih0@x_t + Whh0@h0[prev]   (all operands coherent)
        const float* xb = XT + (size_t)ctr * (II*BB);
        for (int k = ks; k < II; k += 16) {
          f4 hv = ld4c(xb + (k << 6) + rb);
          fma32(acc, *(const f4*)(sWih0 + (k<<3)), *(const f4*)(sWih0 + (k<<3) + 4), hv);
        }
        const float* hb0 = H0 + ((size_t)pp << 14);
        #pragma unroll
        for (int m = 0; m < 16; ++m) {
          int k = ks + (m << 4);
          f4 hv = ld4c(hb0 + (k << 6) + rb);
          fma32(acc, *(const f4*)(sWhh0 + (k<<3)), *(const f4*)(sWhh0 + (k<<3) + 4), hv);
        }
      } else {
        // decoder: gates0 = Wc@relu(h1[prev]) + Whh0@h0[prev]
        const float* hb1 = H1 + ((size_t)pp << 14);
        const float* hb0 = H0 + ((size_t)pp << 14);
        #pragma unroll
        for (int m = 0; m < 16; ++m) {
          int k = ks + (m << 4);
          f4 h1v = ld4c(hb1 + (k << 6) + rb);
          f4 h0v = ld4c(hb0 + (k << 6) + rb);
          h1v.x = fmaxf(h1v.x, 0.f); h1v.y = fmaxf(h1v.y, 0.f);
          h1v.z = fmaxf(h1v.z, 0.f); h1v.w = fmaxf(h1v.w, 0.f);
          fma32(acc, *(const f4*)(sWc   + (k<<3)), *(const f4*)(sWc   + (k<<3) + 4), h1v);
          fma32(acc, *(const f4*)(sWhh0 + (k<<3)), *(const f4*)(sWhh0 + (k<<3) + 4), h0v);
        }
      }
      // gate partial reduce: shfl over (ln&3), per-wave float4 store
      #pragma unroll
      for (int q2 = 0; q2 < 32; ++q2) {
        float v = acc[q2];
        v += __shfl_xor(v, 1, 64); v += __shfl_xor(v, 2, 64);
        acc[q2] = v;
      }
      if ((ln & 3) == 0) {
        #pragma unroll
        for (int g = 0; g < 8; ++g)
          *(float4*)(sGred + (wv << 9) + (g << 6) + rb) =
            make_float4(acc[(g<<2)], acc[(g<<2)+1], acc[(g<<2)+2], acc[(g<<2)+3]);
      }
      // yields head partials (all WGs; 2 WGs per batch)
      if (ctr >= 2 && tid < 128) {
        float zv = __hip_atomic_load(&Zb[((size_t)(ctr & 1) << 13) + ((size_t)tid << 6) + bq],
                                     __ATOMIC_RELAXED, AGENT);
        float yp[5];
        #pragma unroll
        for (int p = 0; p < 5; ++p) yp[p] = zv * sWp2[((pb + p) << 7) + tid];
        #pragma unroll
        for (int p = 0; p < 5; ++p) {
          float v = yp[p];
          v += __shfl_xor(v,1,64); v += __shfl_xor(v,2,64); v += __shfl_xor(v,4,64);
          v += __shfl_xor(v,8,64); v += __shfl_xor(v,16,64); v += __shfl_xor(v,32,64);
          yp[p] = v;
        }
        if (ln == 0) {
          #pragma unroll
          for (int p = 0; p < 5; ++p) sYred[wv][p] = yp[p];
        }
      }
      __syncthreads();
      if (tid < 128) { // gate final sum + bias
        const int boff = (ctr < TT) ? 0 : 8;
        float4 a0 = *(const float4*)(sGred +    0 + (tid<<2));
        float4 a1 = *(const float4*)(sGred +  512 + (tid<<2));
        float4 a2 = *(const float4*)(sGred + 1024 + (tid<<2));
        float4 a3 = *(const float4*)(sGred + 1536 + (tid<<2));
        float bias = sB[boff + (tid >> 4)];
        float4 r;
        r.x = a0.x+a1.x+a2.x+a3.x + bias;
        r.y = a0.y+a1.y+a2.y+a3.y + bias;
        r.z = a0.z+a1.z+a2.z+a3.z + bias;
        r.w = a0.w+a1.w+a2.w+a3.w + bias;
        *(float4*)(sGates + (tid<<2)) = r;
      }
      __syncthreads();
      if (tid < 128) { // LSTM cell, layer 0
        int uu = tid >> 6, r = tid & 63;
        float i_ = sigm (sGates[( uu      << 6) + r]);
        float f_ = sigm (sGates[((2 + uu) << 6) + r]);
        float g_ = tanhf(sGates[((4 + uu) << 6) + r]);
        float o_ = sigm (sGates[((6 + uu) << 6) + r]);
        float c = f_*c0 + i_*g_;
        c0 = c;
        st_wt(&H0[((size_t)(((ctr & 1) << 8) + u0 + uu) << 6) + r], o_*tanhf(c));
      }
      if (ctr >= 2 && tid >= 192 && tid < 197) {
        int p = tid - 192;
        if (pb + p < 9) {
          float y = sYred[0][p] + sYred[1][p] + sB[32 + pb + p];
          st_wt(&out[Y_OFF + ((size_t)bq*QTOT + (ctr - 2))*PPQ + pb + p], y);
        }
      }
    } else { // ctr = 453/454: yields head only
      if (tid < 128) {
        float zv = __hip_atomic_load(&Zb[((size_t)(ctr & 1) << 13) + ((size_t)tid << 6) + bq],
                                     __ATOMIC_RELAXED, AGENT);
        float yp[5];
        #pragma unroll
        for (int p = 0; p < 5; ++p) yp[p] = zv * sWp2[((pb + p) << 7) + tid];
        #pragma unroll
        for (int p = 0; p < 5; ++p) {
          float v = yp[p];
          v += __shfl_xor(v,1,64); v += __shfl_xor(v,2,64); v += __shfl_xor(v,4,64);
          v += __shfl_xor(v,8,64); v += __shfl_xor(v,16,64); v += __shfl_xor(v,32,64);
          yp[p] = v;
        }
        if (ln == 0) {
          #pragma unroll
          for (int p = 0; p < 5; ++p) sYred[wv][p] = yp[p];
        }
      }
      __syncthreads();
      if (tid >= 192 && tid < 197) {
        int p = tid - 192;
        if (pb + p < 9) {
          float y = sYred[0][p] + sYred[1][p] + sB[32 + pb + p];
          st_wt(&out[Y_OFF + ((size_t)bq*QTOT + (ctr - 2))*PPQ + pb + p], y);
        }
      }
    }
    asm volatile("s_waitcnt vmcnt(0)" ::: "memory");
    __syncthreads();
    if (tid == 0) __hip_atomic_store(&flags[wg], phi, __ATOMIC_RELAXED, AGENT);
    if (ctr == 454) break;

    // ========================= PHASE B (layer-1 step + sens/z heads) =========================
    ++phi;
    {
      const int tgt = phi - 1;
      if (tid < NW)
        while (__hip_atomic_load(&flags[tid], __ATOMIC_RELAXED, AGENT) < tgt)
          __builtin_amdgcn_s_sleep(2);
      __syncthreads();
    }
    {
      const int pp = (ctr - 1) & 1, cur = ctr & 1;
      float ps[4] = {0,0,0,0}, pz[4] = {0,0,0,0};

      if (ctr <= 452) {
        float acc[32];
        #pragma unroll
        for (int q2 = 0; q2 < 32; ++q2) acc[q2] = 0.f;

        const float* hbA = H0 + ((size_t)cur << 14);   // h0[ctr]
        const float* hbB = H1 + ((size_t)pp  << 14);   // h1[ctr-1]
        #pragma unroll
        for (int m = 0; m < 16; ++m) {
          int k = ks + (m << 4);
          f4 hv0 = ld4c(hbA + (k << 6) + rb);
          f4 hv1 = ld4c(hbB + (k << 6) + rb);
          fma32(acc, *(const f4*)(sWih1 + (k<<3)), *(const f4*)(sWih1 + (k<<3) + 4), hv0);
          fma32(acc, *(const f4*)(sWhh1 + (k<<3)), *(const f4*)(sWhh1 + (k<<3) + 4), hv1);
          float rx = fmaxf(hv1.x,0.f), ry = fmaxf(hv1.y,0.f), rz = fmaxf(hv1.z,0.f), rw = fmaxf(hv1.w,0.f);
          float wl = sWlin[k], wp = sWp1[k];
          ps[0] += rx*wl; ps[1] += ry*wl; ps[2] += rz*wl; ps[3] += rw*wl;
          pz[0] += rx*wp; pz[1] += ry*wp; pz[2] += rz*wp; pz[3] += rw*wp;
        }
        #pragma unroll
        for (int q2 = 0; q2 < 32; ++q2) {
          float v = acc[q2];
          v += __shfl_xor(v, 1, 64); v += __shfl_xor(v, 2, 64);
          acc[q2] = v;
        }
        #pragma unroll
        for (int j = 0; j < 4; ++j) {
          float v = ps[j]; v += __shfl_xor(v,1,64); v += __shfl_xor(v,2,64); ps[j] = v;
          v = pz[j]; v += __shfl_xor(v,1,64); v += __shfl_xor(v,2,64); pz[j] = v;
        }
        if ((ln & 3) == 0) {
          #pragma unroll
          for (int g = 0; g < 8; ++g)
            *(float4*)(sGred + (wv << 9) + (g << 6) + rb) =
              make_float4(acc[(g<<2)], acc[(g<<2)+1], acc[(g<<2)+2], acc[(g<<2)+3]);
          *(float4*)(sHs + (wv << 6) + rb) = make_float4(ps[0],ps[1],ps[2],ps[3]);
          *(float4*)(sHz + (wv << 6) + rb) = make_float4(pz[0],pz[1],pz[2],pz[3]);
        }
        __syncthreads();
        if (tid < 128) {
          float4 a0 = *(const float4*)(sGred +    0 + (tid<<2));
          float4 a1 = *(const float4*)(sGred +  512 + (tid<<2));
          float4 a2 = *(const float4*)(sGred + 1024 + (tid<<2));
          float4 a3 = *(const float4*)(sGred + 1536 + (tid<<2));
          float bias = sB[16 + (tid >> 4)];
          float4 r;
          r.x = a0.x+a1.x+a2.x+a3.x + bias;
          r.y = a0.y+a1.y+a2.y+a3.y + bias;
          r.z = a0.z+a1.z+a2.z+a3.z + bias;
          r.w = a0.w+a1.w+a2.w+a3.w + bias;
          *(float4*)(sGates + (tid<<2)) = r;
        } else if (tid < 192 && ctr >= 1) { // sens/z finalize, q = ctr-1
          int b = tid - 128, q = ctr - 1;
          float s = sHs[b] + sHs[64+b] + sHs[128+b] + sHs[192+b] + sB[24];
          float z = fmaxf(sHz[b] + sHz[64+b] + sHz[128+b] + sHz[192+b] + sB[25], 0.f);
          if (wg < II) {
            size_t o = (q < TT) ? (SB_OFF + ((size_t)b*TT + q)*II + wg)
                                : (SF_OFF + ((size_t)b*DD + (q - TT))*II + wg);
            st_wt(&out[o], s);
          }
          st_wt(&Zb[((size_t)(q & 1) << 13) + ((size_t)wg << 6) + b], z);
        }
        __syncthreads();
        if (tid < 128) { // LSTM cell, layer 1
          int uu = tid >> 6, r = tid & 63;
          float i_ = sigm (sGates[( uu      << 6) + r]);
          float f_ = sigm (sGates[((2 + uu) << 6) + r]);
          float g_ = tanhf(sGates[((4 + uu) << 6) + r]);
          float o_ = sigm (sGates[((6 + uu) << 6) + r]);
          float c = f_*c1 + i_*g_;
          c1 = c;
          st_wt(&H1[((size_t)((cur << 8) + u0 + uu) << 6) + r], o_*tanhf(c));
        }
      } else { // ctr == 453: heads only from h1[452]
        const float* hbB = H1 + ((size_t)pp << 14);
        #pragma unroll
        for (int m = 0; m < 16; ++m) {
          int k = ks + (m << 4);
          f4 h1v = ld4c(hbB + (k << 6) + rb);
          float rx = fmaxf(h1v.x,0.f), ry = fmaxf(h1v.y,0.f), rz = fmaxf(h1v.z,0.f), rw = fmaxf(h1v.w,0.f);
          float wl = sWlin[k], wp = sWp1[k];
          ps[0] += rx*wl; ps[1] += ry*wl; ps[2] += rz*wl; ps[3] += rw*wl;
          pz[0] += rx*wp; pz[1] += ry*wp; pz[2] += rz*wp; pz[3] += rw*wp;
        }
        #pragma unroll
        for (int j = 0; j < 4; ++j) {
          float v = ps[j]; v += __shfl_xor(v,1,64); v += __shfl_xor(v,2,64); ps[j] = v;
          v = pz[j]; v += __shfl_xor(v,1,64); v += __shfl_xor(v,2,64); pz[j] = v;
        }
        if ((ln & 3) == 0) {
          *(float4*)(sHs + (wv << 6) + rb) = make_float4(ps[0],ps[1],ps[2],ps[3]);
          *(float4*)(sHz + (wv << 6) + rb) = make_float4(pz[0],pz[1],pz[2],pz[3]);
        }
        __syncthreads();
        if (tid >= 128 && tid < 192) {
          int b = tid - 128, q = ctr - 1;
          float s = sHs[b] + sHs[64+b] + sHs[128+b] + sHs[192+b] + sB[24];
          float z = fmaxf(sHz[b] + sHz[64+b] + sHz[128+b] + sHz[192+b] + sB[25], 0.f);
          if (wg < II) {
            size_t o = SF_OFF + ((size_t)b*DD + (q - TT))*II + wg;
            st_wt(&out[o], s);
          }
          st_wt(&Zb[((size_t)(q & 1) << 13) + ((size_t)wg << 6) + b], z);
        }
      }
    }
    asm volatile("s_waitcnt vmcnt(0)" ::: "memory");
    __syncthreads();
    if (tid == 0) __hip_atomic_store(&flags[wg], phi, __ATOMIC_RELAXED, AGENT);
  }
}

extern "C" void kernel_launch(void* const* d_in, const int* in_sizes, int n_in,
                              void* d_out, int out_size, void* d_ws, size_t ws_size,
                              hipStream_t stream) {
  (void)in_sizes; (void)n_in; (void)out_size; (void)ws_size;
  qcm_kernel<<<dim3(NW), dim3(NTHR), 0, stream>>>(
      (const float*)d_in[0],
      (const float*)d_in[1], (const float*)d_in[2], (const float*)d_in[3],
      (const float*)d_in[4], (const float*)d_in[5], (const float*)d_in[6],
      (const float*)d_in[7], (const float*)d_in[8],
      (const float*)d_in[9], (const float*)d_in[10],
      (const float*)d_in[11], (const float*)d_in[12],
      (float*)d_out, (float*)d_ws);
}